// Round 10
// baseline (275.333 us; speedup 1.0000x reference)
//
#include <hip/hip_runtime.h>
#include <hip/hip_bf16.h>

#define B_  2
#define S_  2048
#define D_  1024
#define H_  16
#define DH_ 64

typedef __attribute__((ext_vector_type(8)))  short  short8;
typedef __attribute__((ext_vector_type(4)))  short  short4b;
typedef __attribute__((ext_vector_type(16))) float  f32x16;

#define MFMA32(A,B,C) __builtin_amdgcn_mfma_f32_32x32x16_bf16(A,B,C,0,0,0)

static __device__ __forceinline__ short bf16b(float x) {
    __hip_bfloat16 h = __float2bfloat16(x);
    return *(short*)&h;
}
static __device__ __forceinline__ float bf16tof(short s) {
    union { unsigned u; float f; } cv;
    cv.u = ((unsigned)(unsigned short)s) << 16;
    return cv.f;
}
static __device__ __forceinline__ void gl2lds(const short* g, short* l) {
    __builtin_amdgcn_global_load_lds(
        (const __attribute__((address_space(1))) unsigned int*)g,
        (__attribute__((address_space(3))) unsigned int*)l, 16, 0, 0);
}
static __device__ __forceinline__ unsigned cvtpk(float a, float b) {
    unsigned r;
    asm("v_cvt_pk_bf16_f32 %0, %1, %2" : "=v"(r) : "v"(a), "v"(b));
    return r;   // low16 = bf16(a), high16 = bf16(b)
}
static __device__ __forceinline__ void pl32swap(unsigned &a, unsigned &b) {
    // a[32:63] <-> b[0:31]
    asm volatile("v_permlane32_swap_b32 %0, %1" : "+v"(a), "+v"(b));
}

// ---------------------------------------------------------------------------
// Merged conversion kernel.
//  bid < 12288 : x [4096x1024] fp32 -> hi/lo bf16 (3 z-slices of 4096 blocks)
//  bid >= 12288: w [k][n] fp32 -> wT hi/lo bf16 [n][k] (LDS-transposed tiles)
// ---------------------------------------------------------------------------
__global__ __launch_bounds__(256)
void conv_all(const float* __restrict__ q, const float* __restrict__ k,
              const float* __restrict__ v,
              const float* __restrict__ wq, const float* __restrict__ wk,
              const float* __restrict__ wv, char* __restrict__ ws) {
    __shared__ short HiT[64][80];
    __shared__ short LoT[64][80];
    const int bid = blockIdx.x;
    const int t   = threadIdx.x;
    if (bid < 12288) {
        const int z   = bid >> 12;           // 4096 blocks per z
        const int xb  = bid & 4095;
        const float* src = z == 0 ? q : z == 1 ? k : v;
        short* hi = (short*)(ws + (size_t)z * 16777216);
        short* lo = hi + 4194304;
        const int i = (xb * 256 + t) * 4;
        float4 xv = *(const float4*)&src[i];
        const float* xf = (const float*)&xv;
        short4b h4, l4;
#pragma unroll
        for (int e = 0; e < 4; ++e) {
            short hb = bf16b(xf[e]);
            h4[e] = hb;
            l4[e] = bf16b(xf[e] - bf16tof(hb));
        }
        *(short4b*)&hi[i] = h4;
        *(short4b*)&lo[i] = l4;
        return;
    }
    const int wid = bid - 12288;             // 768 blocks: 3 z x 256
    const int z   = wid >> 8;
    const int rem = wid & 255;
    const int k0  = (rem & 15) << 6, n0 = (rem >> 4) << 6;
    const float* w = z == 0 ? wq : z == 1 ? wk : wv;
    short* oh = (short*)(ws + 50331648 + (size_t)z * 4194304);  // 48MB + z*4MB
    short* ol = oh + 1048576;

    const int kr = t >> 2, c4 = (t & 3) * 16;
    const float* srow = w + (size_t)(k0 + kr) * 1024 + n0 + c4;
#pragma unroll
    for (int u = 0; u < 16; u += 4) {
        float4 f = *(const float4*)&srow[u];
        const float* ff = (const float*)&f;
#pragma unroll
        for (int e = 0; e < 4; ++e) {
            int nl = c4 + u + e;
            short hb = bf16b(ff[e]);
            HiT[nl][kr] = hb;
            LoT[nl][kr] = bf16b(ff[e] - bf16tof(hb));
        }
    }
    __syncthreads();
    const int nl = t >> 2, kc = (t & 3) * 16;
    size_t off = (size_t)(n0 + nl) * 1024 + k0 + kc;
    *(short8*)&oh[off]     = *(const short8*)&HiT[nl][kc];
    *(short8*)&oh[off + 8] = *(const short8*)&HiT[nl][kc + 8];
    *(short8*)&ol[off]     = *(const short8*)&LoT[nl][kc];
    *(short8*)&ol[off + 8] = *(const short8*)&LoT[nl][kc + 8];
}

// ---------------------------------------------------------------------------
// MFMA hi/lo projection GEMM — unchanged from round 9 (256x256 4-phase,
// 0 bank conflicts, FETCH halved vs 128-tile; at its structure plateau).
// ---------------------------------------------------------------------------
#define AH_ 0
#define AL_ 8192
#define BH_ 16384
#define BL_ 24576

__global__ __launch_bounds__(512, 2)
void proj_mfma(const short* __restrict__ xh0, const short* __restrict__ xl0,
               const short* __restrict__ xh1, const short* __restrict__ xl1,
               const short* __restrict__ xh2, const short* __restrict__ xl2,
               const short* __restrict__ wh0, const short* __restrict__ wl0,
               const short* __restrict__ wh1, const short* __restrict__ wl1,
               const short* __restrict__ wh2, const short* __restrict__ wl2,
               short* __restrict__ qh, short* __restrict__ ql,
               short* __restrict__ kh, short* __restrict__ kl,
               short* __restrict__ vt) {
    __shared__ __align__(16) short lds[65536];   // 128 KB: 2 x 4 x [256][32]
    const int z  = blockIdx.z;
    const int m0 = blockIdx.y * 256;
    const int n0 = blockIdx.x * 256;
    const int t = threadIdx.x, lane = t & 63, w = t >> 6;
    const int l31 = lane & 31, hh = lane >> 5;
    const int wr = w >> 2, wc = w & 3;           // wave tile 128x64

    const short* xh = z == 0 ? xh0 : z == 1 ? xh1 : xh2;
    const short* xl = z == 0 ? xl0 : z == 1 ? xl1 : xl2;
    const short* wh = z == 0 ? wh0 : z == 1 ? wh1 : wh2;
    const short* wl = z == 0 ? wl0 : z == 1 ? wl1 : wl2;

    // staging: arrays 0=Ah 1=Al 2=Bh 3=Bl, 1024 chunks each, 2 per thread
    const short* gs[8];
    short*       ld8[8];
#pragma unroll
    for (int j = 0; j < 8; ++j) {
        const int arr = j >> 1;
        const int cc  = t + ((j & 1) << 9);      // 0..1023
        const int row = cc >> 2, p = cc & 3;
        const int kc  = p ^ ((row & 3) ^ ((row >> 2) & 3));
        const short* base = arr == 0 ? xh : arr == 1 ? xl : arr == 2 ? wh : wl;
        const int r0g = (arr < 2) ? m0 : n0;
        gs[j]  = base + (size_t)(r0g + row) * 1024 + kc * 8;
        ld8[j] = &lds[arr * 8192 + ((j & 1) << 12) + (w << 9)];  // wave-uniform
    }

    // read addressing: row*32 + ((kc ^ swl) << 3), kc = (ks<<1)|hh
    const int swl = (l31 & 3) ^ ((l31 >> 2) & 3);
    const int co0 = (hh ^ swl) << 3;
    const int co1 = ((2 | hh) ^ swl) << 3;
    int rA[4], rB[2];
#pragma unroll
    for (int p = 0; p < 4; ++p) rA[p] = (wr * 128 + p * 32 + l31) * 32;
#pragma unroll
    for (int n = 0; n < 2; ++n) rB[n] = (wc * 64 + n * 32 + l31) * 32;

    f32x16 acc[4][2] = {};

    // prologue: tile 0 -> buffer 0, publish
#pragma unroll
    for (int j = 0; j < 8; ++j)
        gl2lds(gs[j], ld8[j]);
    asm volatile("s_waitcnt vmcnt(0)" ::: "memory");
    __builtin_amdgcn_s_barrier();

#define PHASE_MFMA(PA, PB)                                                    \
    acc[PA][0] = MFMA32(ah0, bh0k, acc[PA][0]);                               \
    acc[PA][1] = MFMA32(ah0, bh1k, acc[PA][1]);                               \
    acc[PB][0] = MFMA32(ah1, bh0k, acc[PB][0]);                               \
    acc[PB][1] = MFMA32(ah1, bh1k, acc[PB][1]);                               \
    acc[PA][0] = MFMA32(ah0, bl0k, acc[PA][0]);                               \
    acc[PA][1] = MFMA32(ah0, bl1k, acc[PA][1]);                               \
    acc[PB][0] = MFMA32(ah1, bl0k, acc[PB][0]);                               \
    acc[PB][1] = MFMA32(ah1, bl1k, acc[PB][1]);                               \
    acc[PA][0] = MFMA32(al0, bh0k, acc[PA][0]);                               \
    acc[PA][1] = MFMA32(al0, bh1k, acc[PA][1]);                               \
    acc[PB][0] = MFMA32(al1, bh0k, acc[PB][0]);                               \
    acc[PB][1] = MFMA32(al1, bh1k, acc[PB][1]);

    for (int kt = 0; kt < 32; ++kt) {
        const int tb = (kt & 1) << 15;           // current buffer (shorts)
        const int nbo = 32768 - tb;              // next buffer offset
        const int nk = (kt + 1) * 32;
        const bool st = (kt < 31);

        short8 bh0k, bh1k, bl0k, bl1k, ah0, ah1, al0, al1;

        // ===== P0: ks0, rows {0,1}; stage Ah(t+1) =====
        __builtin_amdgcn_sched_barrier(0);
        bh0k = *(const short8*)&lds[tb + BH_ + rB[0] + co0];
        bh1k = *(const short8*)&lds[tb + BH_ + rB[1] + co0];
        bl0k = *(const short8*)&lds[tb + BL_ + rB[0] + co0];
        bl1k = *(const short8*)&lds[tb + BL_ + rB[1] + co0];
        ah0  = *(const short8*)&lds[tb + AH_ + rA[0] + co0];
        ah1  = *(const short8*)&lds[tb + AH_ + rA[1] + co0];
        al0  = *(const short8*)&lds[tb + AL_ + rA[0] + co0];
        al1  = *(const short8*)&lds[tb + AL_ + rA[1] + co0];
        if (st) { gl2lds(gs[0] + nk, ld8[0] + nbo);
                  gl2lds(gs[1] + nk, ld8[1] + nbo); }
        __builtin_amdgcn_s_barrier();
        asm volatile("s_waitcnt lgkmcnt(0)" ::: "memory");
        __builtin_amdgcn_sched_barrier(0);
        __builtin_amdgcn_s_setprio(1);
        PHASE_MFMA(0, 1)
        __builtin_amdgcn_s_setprio(0);
        __builtin_amdgcn_sched_barrier(0);
        __builtin_amdgcn_s_barrier();

        // ===== P1: ks0, rows {2,3}; stage Al(t+1) =====
        __builtin_amdgcn_sched_barrier(0);
        ah0 = *(const short8*)&lds[tb + AH_ + rA[2] + co0];
        ah1 = *(const short8*)&lds[tb + AH_ + rA[3] + co0];
        al0 = *(const short8*)&lds[tb + AL_ + rA[2] + co0];
        al1 = *(const short8*)&lds[tb + AL_ + rA[3] + co0];
        if (st) { gl2lds(gs[2] + nk, ld8[2] + nbo);
                  gl2lds(gs[3] + nk, ld8[3] + nbo); }
        __builtin_amdgcn_s_barrier();
        asm volatile("s_waitcnt lgkmcnt(0)" ::: "memory");
        __builtin_amdgcn_sched_barrier(0);
        __builtin_amdgcn_s_setprio(1);
        PHASE_MFMA(2, 3)
        __builtin_amdgcn_s_setprio(0);
        __builtin_amdgcn_sched_barrier(0);
        __builtin_amdgcn_s_barrier();

        // ===== P2: ks1, rows {0,1}; stage Bh+Bl(t+1) =====
        __builtin_amdgcn_sched_barrier(0);
        bh0k = *(const short8*)&lds[tb + BH_ + rB[0] + co1];
        bh1k = *(const short8*)&lds[tb + BH_ + rB[1] + co1];
        bl0k = *(const short8*)&lds[tb + BL_ + rB[0] + co1];
        bl1k = *(const short8*)&lds[tb + BL_ + rB[1] + co1];
        ah0  = *(const short8*)&lds[tb + AH_ + rA[0] + co1];
        ah1  = *(const short8*)&lds[tb + AH_ + rA[1] + co1];
        al0  = *(const short8*)&lds[tb + AL_ + rA[0] + co1];
        al1  = *(const short8*)&lds[tb + AL_ + rA[1] + co1];
        if (st) { gl2lds(gs[4] + nk, ld8[4] + nbo);
                  gl2lds(gs[5] + nk, ld8[5] + nbo);
                  gl2lds(gs[6] + nk, ld8[6] + nbo);
                  gl2lds(gs[7] + nk, ld8[7] + nbo); }
        __builtin_amdgcn_s_barrier();
        asm volatile("s_waitcnt lgkmcnt(0)" ::: "memory");
        __builtin_amdgcn_sched_barrier(0);
        __builtin_amdgcn_s_setprio(1);
        PHASE_MFMA(0, 1)
        __builtin_amdgcn_s_setprio(0);
        __builtin_amdgcn_sched_barrier(0);
        __builtin_amdgcn_s_barrier();

        // ===== P3: ks1, rows {2,3}; publish next tile at end =====
        __builtin_amdgcn_sched_barrier(0);
        ah0 = *(const short8*)&lds[tb + AH_ + rA[2] + co1];
        ah1 = *(const short8*)&lds[tb + AH_ + rA[3] + co1];
        al0 = *(const short8*)&lds[tb + AL_ + rA[2] + co1];
        al1 = *(const short8*)&lds[tb + AL_ + rA[3] + co1];
        __builtin_amdgcn_s_barrier();
        asm volatile("s_waitcnt lgkmcnt(0)" ::: "memory");
        __builtin_amdgcn_sched_barrier(0);
        __builtin_amdgcn_s_setprio(1);
        PHASE_MFMA(2, 3)
        __builtin_amdgcn_s_setprio(0);
        __builtin_amdgcn_sched_barrier(0);
        // only next-tile's 8 loads are outstanding here (~3 phases of cover)
        asm volatile("s_waitcnt vmcnt(0)" ::: "memory");
        __builtin_amdgcn_s_barrier();
    }
#undef PHASE_MFMA

    // ---- epilogue ----
    const int bb = m0 >> 11;
    const int sbase = (m0 & 2047) + wr * 128;
    if (z < 2) {
        short* oh = z == 0 ? qh : kh;
        short* ol = z == 0 ? ql : kl;
        const float qs = (z == 0) ? 0.125f : 1.0f;   // fold attn scale into Q
#pragma unroll
        for (int p = 0; p < 4; ++p)
#pragma unroll
        for (int nt = 0; nt < 2; ++nt) {
            int n_g = n0 + wc * 64 + nt * 32 + l31;
            int h = n_g >> 6, d = n_g & 63;
#pragma unroll
            for (int r = 0; r < 16; ++r) {
                int s = sbase + p * 32 + (r & 3) + 8 * (r >> 2) + 4 * hh;
                size_t off = (((size_t)(bb * 16 + h) * 2048 + s) << 6) + d;
                float a = acc[p][nt][r] * qs;
                short hb = bf16b(a);
                oh[off] = hb;
                ol[off] = bf16b(a - bf16tof(hb));
            }
        }
    } else {
#pragma unroll
        for (int p = 0; p < 4; ++p)
#pragma unroll
        for (int nt = 0; nt < 2; ++nt) {
            int n_g = n0 + wc * 64 + nt * 32 + l31;
            int h = n_g >> 6, d = n_g & 63;
            size_t vbase = ((size_t)(bb * 16 + h) * 64 + d) * 2048;
#pragma unroll
            for (int r2 = 0; r2 < 4; ++r2) {
                int s0 = sbase + p * 32 + 8 * r2 + 4 * hh;
                short4b pk;
#pragma unroll
                for (int a2 = 0; a2 < 4; ++a2)
                    pk[a2] = bf16b(acc[p][nt][r2 * 4 + a2]);
                *(short4b*)&vt[vbase + s0] = pk;
            }
        }
    }
}

// ---------------------------------------------------------------------------
// MFMA flash attention — round 10: split-k for heavy q-tiles.
//  yy < 8  : qt = yy, full range (2qt+2 tiles), normal epilogue (bit-identical
//            to round 9 for these rows).
//  yy >= 8 : j=(yy-8)>>1, s=(yy-8)&1, qt=8+j; this block processes half the
//            key range (h = qt+1 tiles starting at s*h) and writes
//            UNNORMALIZED partials (O, m, l) to PB; attn_combine merges.
// Critical path drops 34 -> 16 tile-units; 768 blocks fill 512 CU slots.
// ---------------------------------------------------------------------------
__global__ __launch_bounds__(256, 2)
void attn_mfma(const short* __restrict__ Qhi, const short* __restrict__ Qlo,
               const short* __restrict__ Khi, const short* __restrict__ Klo,
               const short* __restrict__ Vt,  float* __restrict__ PB,
               float* __restrict__ out) {
    __shared__ __align__(16) short SBUF[24576];   // 48KB: Khi|Klo|Vt (dbuf each)
    __shared__ float svp[4][64];
    __shared__ float svs[64];
#define KhiS (SBUF)
#define KloS (SBUF + 8192)
#define VtS  (SBUF + 16384)

    const int t     = threadIdx.x;
    const int lane  = t & 63;
    const int w     = t >> 6;
    const int l31   = lane & 31;
    const int hh    = lane >> 5;
    const int bh    = blockIdx.x;
    const int yy    = blockIdx.y;

    int qt, kt0, ktn;          // q-tile, first k-tile, #tiles this block
    bool full;
    if (yy < 8) { qt = yy;             full = true;  kt0 = 0; ktn = 2 * qt + 2; }
    else { int j = (yy - 8) >> 1, s = (yy - 8) & 1;
           qt = 8 + j;                 full = false;
           int hseg = qt + 1;          kt0 = s * hseg; ktn = hseg; }

    const int q0    = qt * 128;
    const int myq   = q0 + w * 32 + l31;
    const int myq_min = q0 + w * 32;
    const int ktend = 2 * qt + 2;

    const size_t basebh = (size_t)bh * S_ * DH_;

    // ---- in-block V suffix sum (only full blocks need it) ----
    if (full) {
        const int s_begin = ktend * 64;
        float part = 0.f;
        const short* vrow = Vt + basebh + (size_t)lane * S_;
        for (int s = s_begin + w * 8; s < S_; s += 32) {
            short8 vv = *(const short8*)&vrow[s];
#pragma unroll
            for (int e = 0; e < 8; ++e) part += bf16tof(vv[e]);
        }
        svp[w][lane] = part;
        __syncthreads();
        if (t < 64)
            svs[t] = svp[0][t] + svp[1][t] + svp[2][t] + svp[3][t];
    }

    short8 qh[4], ql[4];
    {
        const short* qr = Qhi + basebh + (size_t)myq * DH_;
        const short* lr = Qlo + basebh + (size_t)myq * DH_;
#pragma unroll
        for (int kf = 0; kf < 4; ++kf) {
            int dofs = kf * 16 + hh * 8;
            qh[kf] = *(const short8*)(qr + dofs);
            ql[kf] = *(const short8*)(lr + dofs);
        }
    }

    // staging descriptors: 512 16B-chunks per 64x64 tile, 2 per thread.
    const int i1 = (w << 6) | lane;       // 0..255
    const int i2 = 256 + i1;              // 256..511
    const int r1 = i1 >> 3, c1 = (i1 & 7) ^ (r1 & 7);
    const int r2 = i2 >> 3, c2 = (i2 & 7) ^ (r2 & 7);
    const short* gKh1 = Khi + basebh + (size_t)r1 * 64 + c1 * 8;
    const short* gKh2 = Khi + basebh + (size_t)r2 * 64 + c2 * 8;
    const short* gKl1 = Klo + basebh + (size_t)r1 * 64 + c1 * 8;
    const short* gKl2 = Klo + basebh + (size_t)r2 * 64 + c2 * 8;
    const short* gV1  = Vt  + basebh + (size_t)r1 * S_ + c1 * 8;
    const short* gV2  = Vt  + basebh + (size_t)r2 * S_ + c2 * 8;
    const int wub = w << 9;               // wave-uniform lds base (shorts)

#define ASTAGE(KT, BUF) do {                                                  \
        const int ka_ = (KT) * 4096, va_ = (KT) * 64, bo_ = (BUF) * 4096;     \
        gl2lds(gKh1 + ka_, &KhiS[bo_ + wub]);                                 \
        gl2lds(gKh2 + ka_, &KhiS[bo_ + 2048 + wub]);                          \
        gl2lds(gKl1 + ka_, &KloS[bo_ + wub]);                                 \
        gl2lds(gKl2 + ka_, &KloS[bo_ + 2048 + wub]);                          \
        gl2lds(gV1  + va_, &VtS [bo_ + wub]);                                 \
        gl2lds(gV2  + va_, &VtS [bo_ + 2048 + wub]);                          \
    } while (0)

    float m_run = -INFINITY, l_run = 0.f;
    f32x16 oT0 = {}, oT1 = {};

    const int sw0 = l31 & 7;              // read-swizzle ((l31+32)&7 == l31&7)

    ASTAGE(kt0, 0);

    for (int idx = 0; idx < ktn; ++idx) {
        const int kt = kt0 + idx;
        const int bo = (idx & 1) << 12;
        asm volatile("s_waitcnt vmcnt(0)" ::: "memory");
        __builtin_amdgcn_s_barrier();
        __builtin_amdgcn_sched_barrier(0);   // no hoisting above the barrier
        if (idx + 1 < ktn)
            ASTAGE(kt + 1, (idx & 1) ^ 1);
        __builtin_amdgcn_sched_barrier(0);   // keep stage issue before compute

        f32x16 acc0 = {}, acc1 = {};
        __builtin_amdgcn_s_setprio(1);
#pragma unroll
        for (int kf = 0; kf < 4; ++kf) {
            const int cs = ((2 * kf + hh) ^ sw0) << 3;
            short8 k0h = *(const short8*)&KhiS[bo + l31 * 64 + cs];
            short8 k0l = *(const short8*)&KloS[bo + l31 * 64 + cs];
            short8 k1h = *(const short8*)&KhiS[bo + (l31 + 32) * 64 + cs];
            short8 k1l = *(const short8*)&KloS[bo + (l31 + 32) * 64 + cs];
            acc0 = MFMA32(k0h, qh[kf], acc0);
            acc0 = MFMA32(k0h, ql[kf], acc0);
            acc0 = MFMA32(k0l, qh[kf], acc0);
            acc1 = MFMA32(k1h, qh[kf], acc1);
            acc1 = MFMA32(k1h, ql[kf], acc1);
            acc1 = MFMA32(k1l, qh[kf], acc1);
        }
        __builtin_amdgcn_s_setprio(0);

        float vals[32];
        float tmax;
        if (kt * 64 + 63 <= myq_min) {
            // fully-unmasked tile (wave-uniform): vals = acc directly
            float t0 = -INFINITY, t1 = -INFINITY;
#pragma unroll
            for (int r = 0; r < 16; ++r) {
                vals[r]      = acc0[r];
                vals[16 + r] = acc1[r];
                t0 = fmaxf(t0, acc0[r]);
                t1 = fmaxf(t1, acc1[r]);
            }
            tmax = fmaxf(t0, t1);
        } else {
            tmax = -INFINITY;
#pragma unroll
            for (int r = 0; r < 16; ++r) {
                int key0 = kt * 64 + ((r & 3) + 8 * (r >> 2) + 4 * hh);
                float v0 = (key0 <= myq)      ? acc0[r] : -8.0f;
                float v1 = (key0 + 32 <= myq) ? acc1[r] : -8.0f;
                vals[r] = v0;
                vals[16 + r] = v1;
                tmax = fmaxf(tmax, fmaxf(v0, v1));
            }
        }
        tmax = fmaxf(tmax, __shfl_xor(tmax, 32, 64));
        // defer-max (T13)
        const bool defer = __all(tmax <= m_run + 8.0f);
        if (!defer) {
            float mnew  = fmaxf(m_run, tmax);
            float alpha = __expf(m_run - mnew);
            l_run *= alpha;
#pragma unroll
            for (int r = 0; r < 16; ++r) { oT0[r] *= alpha; oT1[r] *= alpha; }
            m_run = mnew;
        }
        // T12: exp + pack in-register; psum on unrounded values.
        float psum = 0.f;
        unsigned cw[16];
#pragma unroll
        for (int tt = 0; tt < 16; ++tt) {
            float p0 = __expf(vals[2 * tt]     - m_run);
            float p1 = __expf(vals[2 * tt + 1] - m_run);
            psum += p0 + p1;
            cw[tt] = cvtpk(p0, p1);
        }
        psum += __shfl_xor(psum, 32, 64);
        l_run += psum;

        __builtin_amdgcn_s_setprio(1);
#pragma unroll
        for (int kf = 0; kf < 4; ++kf) {
            unsigned w0 = cw[4 * kf],     w1 = cw[4 * kf + 1];
            unsigned w2 = cw[4 * kf + 2], w3 = cw[4 * kf + 3];
            pl32swap(w0, w2);
            pl32swap(w1, w3);
            union { unsigned u[4]; short8 s8; } pu;
            pu.u[0] = w0; pu.u[1] = w1; pu.u[2] = w2; pu.u[3] = w3;
            const int cs = ((2 * kf + hh) ^ sw0) << 3;
            short8 v0 = *(const short8*)&VtS[bo + l31 * 64 + cs];
            short8 v1 = *(const short8*)&VtS[bo + (l31 + 32) * 64 + cs];
            oT0 = MFMA32(v0, pu.s8, oT0);
            oT1 = MFMA32(v1, pu.s8, oT1);
        }
        __builtin_amdgcn_s_setprio(0);
        __builtin_amdgcn_sched_barrier(0);
    }
#undef ASTAGE

    if (!full) {
        // write unnormalized partials: [bh][j][s]{ O[128][64], m[128], l[128] }
        const int j = qt - 8, s = (kt0 != 0);
        float* seg = PB + (((size_t)bh * 8 + j) * 2 + s) * 8448;
        const int row = w * 32 + l31;
#pragma unroll
        for (int r = 0; r < 16; ++r) {
            int d0 = (r & 3) + 8 * (r >> 2) + 4 * hh;
            seg[row * 64 + d0]      = oT0[r];
            seg[row * 64 + d0 + 32] = oT1[r];
        }
        if (hh == 0) { seg[8192 + row] = m_run; seg[8320 + row] = l_run; }
        return;
    }

    {
        float mfin = fmaxf(m_run, -8.0f);
        float aa   = __expf(m_run - mfin);
        float e8   = __expf(-8.0f - mfin);
        float nrem = (float)(S_ - ktend * 64);
        float lfin = l_run * aa + nrem * e8;
        float inv  = 1.0f / lfin;
#pragma unroll
        for (int r = 0; r < 16; ++r) {
            int dim0 = (r & 3) + 8 * (r >> 2) + 4 * hh;
            oT0[r] = (oT0[r] * aa + e8 * svs[dim0])      * inv;
            oT1[r] = (oT1[r] * aa + e8 * svs[dim0 + 32]) * inv;
        }
    }

    __syncthreads();
    float* Ob = (float*)SBUF + w * 2176;   // 32 rows x 68 floats per wave
#pragma unroll
    for (int r = 0; r < 16; ++r) {
        int dim0 = (r & 3) + 8 * (r >> 2) + 4 * hh;
        Ob[l31 * 68 + dim0]      = oT0[r];
        Ob[l31 * 68 + dim0 + 32] = oT1[r];
    }
    {
        const int qq = lane >> 1;
        const int ch = (lane & 1) * 32;
        const float* src = Ob + qq * 68 + ch;
        const int b  = bh >> 4;
        const int h  = bh & 15;
        float* dst = out + ((size_t)b * S_ + (q0 + w * 32 + qq)) * D_ + h * 64 + ch;
#pragma unroll
        for (int c = 0; c < 32; c += 4)
            *(float4*)(dst + c) = *(const float4*)(src + c);
    }
#undef KhiS
#undef KloS
#undef VtS
}

// ---------------------------------------------------------------------------
// Combine the two key-range segments for heavy q-tiles (qt = 8..15) and
// apply the all-masked-tail correction + normalization.
// grid: 256 blocks = (bh 0..31) x (j 0..7); 256 threads (2 per q-row).
// ---------------------------------------------------------------------------
__global__ __launch_bounds__(256)
void attn_combine(const float* __restrict__ PB, const short* __restrict__ Vt,
                  float* __restrict__ out) {
    __shared__ float svp[4][64];
    __shared__ float svs[64];
    const int bh = blockIdx.x >> 3, j = blockIdx.x & 7;
    const int qt = 8 + j, ktend = 2 * qt + 2;
    const int nrem = S_ - ktend * 64;
    const int t = threadIdx.x;

    // V suffix sums for the all-masked tail
    {
        const int d = t & 63, g = t >> 6;
        float part = 0.f;
        const short* vrow = Vt + (size_t)bh * DH_ * S_ + (size_t)d * S_;
        for (int s = ktend * 64 + g * 8; s < S_; s += 32) {
            short8 vv = *(const short8*)&vrow[s];
#pragma unroll
            for (int e = 0; e < 8; ++e) part += bf16tof(vv[e]);
        }
        svp[g][d] = part;
    }
    __syncthreads();
    if (t < 64) svs[t] = svp[0][t] + svp[1][t] + svp[2][t] + svp[3][t];
    __syncthreads();

    const float* s0 = PB + (((size_t)bh * 8 + j) * 2) * 8448;
    const float* s1 = s0 + 8448;
    const int row = t >> 1, half = (t & 1) * 32;

    const float m0 = s0[8192 + row], l0 = s0[8320 + row];
    const float m1 = s1[8192 + row], l1 = s1[8320 + row];
    const float m    = fmaxf(m0, m1);
    const float mfin = fmaxf(m, -8.0f);
    const float a0 = __expf(m0 - mfin), a1 = __expf(m1 - mfin);
    const float e8 = __expf(-8.0f - mfin);
    const float lfin = l0 * a0 + l1 * a1 + (float)nrem * e8;
    const float inv = 1.0f / lfin;

    const int b = bh >> 4, h = bh & 15;
    float* dst = out + ((size_t)b * S_ + qt * 128 + row) * D_ + h * 64 + half;
    const float* O0 = s0 + row * 64 + half;
    const float* O1 = s1 + row * 64 + half;
#pragma unroll
    for (int c = 0; c < 32; c += 4) {
        float4 o0 = *(const float4*)(O0 + c);
        float4 o1 = *(const float4*)(O1 + c);
        float4 r;
        r.x = (o0.x * a0 + o1.x * a1 + e8 * svs[half + c + 0]) * inv;
        r.y = (o0.y * a0 + o1.y * a1 + e8 * svs[half + c + 1]) * inv;
        r.z = (o0.z * a0 + o1.z * a1 + e8 * svs[half + c + 2]) * inv;
        r.w = (o0.w * a0 + o1.w * a1 + e8 * svs[half + c + 3]) * inv;
        *(float4*)(dst + c) = r;
    }
}

// ---------------------------------------------------------------------------
extern "C" void kernel_launch(void* const* d_in, const int* in_sizes, int n_in,
                              void* d_out, int out_size, void* d_ws, size_t ws_size,
                              hipStream_t stream) {
    const float* q  = (const float*)d_in[0];
    const float* k  = (const float*)d_in[1];
    const float* v  = (const float*)d_in[2];
    const float* wq = (const float*)d_in[4];
    const float* wk = (const float*)d_in[5];
    const float* wv = (const float*)d_in[6];
    float* out = (float*)d_out;

    char* ws = (char*)d_ws;
    // ws layout: x hi/lo [z]: z*16MB (+8MB for lo); wT hi/lo [z]: 48MB + z*4MB
    const short* XH[3] = {(short*)ws, (short*)(ws + 16777216), (short*)(ws + 33554432)};
    const short* XL[3] = {XH[0] + 4194304, XH[1] + 4194304, XH[2] + 4194304};
    const short* WH[3] = {(short*)(ws + 50331648), (short*)(ws + 54525952), (short*)(ws + 58720256)};
    const short* WL[3] = {WH[0] + 1048576, WH[1] + 1048576, WH[2] + 1048576};

    // attn split-k partials: reuse the x hi/lo region (dead after proj_mfma).
    float* PB = (float*)ws;   // 32*8*2*8448 floats = 16.5 MB

    // Q/K/V projection outputs: workspace if it's big enough (keeps the
    // harness's input buffers clean); tightly packed at 60MB..100MB.
    short *Qhi, *Qlo, *Khi, *Klo, *Vt;
    if (ws_size >= (size_t)104857600) {            // 100 MB
        Qhi = (short*)(ws + 62914560);
        Qlo = (short*)(ws + 71303168);
        Khi = (short*)(ws + 79691776);
        Klo = (short*)(ws + 88080384);
        Vt  = (short*)(ws + 96468992);
    } else {
        Qhi = (short*)d_in[0]; Qlo = Qhi + 4194304;
        Khi = (short*)d_in[1]; Klo = Khi + 4194304;
        Vt  = (short*)d_in[2];
    }

    conv_all<<<dim3(13056), 256, 0, stream>>>(q, k, v, wq, wk, wv, ws);

    proj_mfma<<<dim3(4, 16, 3), 512, 0, stream>>>(
        XH[0], XL[0], XH[1], XL[1], XH[2], XL[2],
        WH[0], WL[0], WH[1], WL[1], WH[2], WL[2],
        Qhi, Qlo, Khi, Klo, Vt);

    attn_mfma<<<dim3(32, 24), 256, 0, stream>>>(Qhi, Qlo, Khi, Klo, Vt, PB, out);

    attn_combine<<<dim3(256), 256, 0, stream>>>(PB, Vt, out);
}